// Round 8
// baseline (96.335 us; speedup 1.0000x reference)
//
#include <hip/hip_runtime.h>

// Problem constants (fixed by the reference)
#define BB 2048
#define CC 50
#define DD 512
#define HH 51     // D // 10
#define RPB 16    // FFN rows per block

static __device__ __forceinline__ float dot4(const float4 a, const float4 b) {
    return a.x * b.x + a.y * b.y + a.z * b.z + a.w * b.w;
}

// ---------------- Kernel 1: gather + pooled (R3 proven body, FFN removed) ----
// grid BB, block 512 (8 waves). Writes pooled[b] (512 f32) to ws.
__global__ __launch_bounds__(512) void gather_pool_kernel(
    const float* __restrict__ q,      // [B, D]
    const int*   __restrict__ heads,  // [B, C]
    const int*   __restrict__ tails,  // [B, C]
    const int*   __restrict__ rels,   // [B, C]
    const float* __restrict__ ent,    // [NE+1, D]
    const float* __restrict__ rel,    // [NR+1, D]
    float* __restrict__ ws_pool)      // [B, D]
{
    const int b    = blockIdx.x;
    const int tid  = threadIdx.x;
    const int wave = tid >> 6;
    const int lane = tid & 63;

    __shared__ float  s_q[DD];          // 2 KB
    __shared__ float4 s_pp[8][128];     // 16 KB per-wave partials
    __shared__ int    s_h[CC], s_t[CC], s_r[CC];

    if (tid < CC) {
        s_h[tid] = heads[b * CC + tid];
        s_t[tid] = tails[b * CC + tid];
        s_r[tid] = rels [b * CC + tid];
    }
    if (tid < 128) {
        ((float4*)s_q)[tid] = ((const float4*)(q + (size_t)b * DD))[tid];
    }
    __syncthreads();

    const float4 q0 = ((const float4*)s_q)[lane * 2];
    const float4 q1 = ((const float4*)s_q)[lane * 2 + 1];

    float4 acc0 = make_float4(0.f, 0.f, 0.f, 0.f);
    float4 acc1 = make_float4(0.f, 0.f, 0.f, 0.f);
    #pragma unroll 2
    for (int c = wave; c < CC; c += 8) {
        const float4* hrow = (const float4*)(ent + (size_t)s_h[c] * DD);
        const float4* trow = (const float4*)(ent + (size_t)s_t[c] * DD);
        const float4* rrow = (const float4*)(rel + (size_t)s_r[c] * DD);
        const float4 h0 = hrow[lane * 2];
        const float4 h1 = hrow[lane * 2 + 1];
        const float4 t0 = trow[lane * 2];
        const float4 t1 = trow[lane * 2 + 1];
        const float4 r0 = rrow[lane * 2];
        const float4 r1 = rrow[lane * 2 + 1];
        float p = dot4(q0, h0) + dot4(q1, h1);
        #pragma unroll
        for (int off = 32; off > 0; off >>= 1) p += __shfl_xor(p, off, 64);
        acc0.x += p * (t0.x + r0.x);
        acc0.y += p * (t0.y + r0.y);
        acc0.z += p * (t0.z + r0.z);
        acc0.w += p * (t0.w + r0.w);
        acc1.x += p * (t1.x + r1.x);
        acc1.y += p * (t1.y + r1.y);
        acc1.z += p * (t1.z + r1.z);
        acc1.w += p * (t1.w + r1.w);
    }
    s_pp[wave][lane * 2]     = acc0;
    s_pp[wave][lane * 2 + 1] = acc1;
    __syncthreads();

    if (tid < 128) {
        float4 s = s_pp[0][tid];
        #pragma unroll
        for (int w = 1; w < 8; ++w) {
            const float4 a = s_pp[w][tid];
            s.x += a.x; s.y += a.y; s.z += a.z; s.w += a.w;
        }
        ((float4*)(ws_pool + (size_t)b * DD))[tid] = s;
    }
}

// ---------------- Kernel 2: batched FFN + residual -----------------------
// grid BB/RPB = 128 blocks, block 512 (8 waves). Wave w owns rows 2w, 2w+1.
// pooled[r][d] is wave-uniform -> scalar loads; w1/w2 reads lane-coalesced,
// amortized across 16 rows per block (~300 KB/block vs 208 KB/row before).
__global__ __launch_bounds__(512) void ffn_kernel(
    const float* __restrict__ q,        // [B, D]
    const float* __restrict__ ws_pool,  // [B, D]
    const float* __restrict__ w1,       // [D, H]
    const float* __restrict__ b1,       // [H]
    const float* __restrict__ w2,       // [H, D]
    const float* __restrict__ b2,       // [D]
    float* __restrict__ out)            // [B, D]
{
    const int tid   = threadIdx.x;
    const int wave  = __builtin_amdgcn_readfirstlane(tid >> 6);  // force SGPR
    const int lane  = tid & 63;
    const int b0    = blockIdx.x * RPB;
    const int r0    = b0 + wave * 2;
    const int r1    = r0 + 1;

    __shared__ float s_mid[RPB][52];   // padded

    // ---- layer 1: mid[r] = relu(pooled[r] @ w1 + b1), wave-local ----
    if (lane < HH) {
        const float* __restrict__ P0 = ws_pool + (size_t)r0 * DD;
        const float* __restrict__ P1 = ws_pool + (size_t)r1 * DD;
        float m0 = 0.f, m1 = 0.f;
        #pragma unroll 8
        for (int d = 0; d < DD; ++d) {
            const float w = w1[(size_t)d * HH + lane];   // 51-lane coalesced
            const float p0 = P0[d];                      // wave-uniform -> s_load
            const float p1 = P1[d];
            m0 += p0 * w;
            m1 += p1 * w;
        }
        const float bb = b1[lane];
        m0 += bb; m1 += bb;
        s_mid[wave * 2][lane]     = m0 > 0.f ? m0 : 0.f;
        s_mid[wave * 2 + 1][lane] = m1 > 0.f ? m1 : 0.f;
    }
    __syncthreads();

    // ---- layer 2: out[r] = mid[r] @ w2 + b2 + q[r], wave-local ----
    float4 a00 = make_float4(0.f, 0.f, 0.f, 0.f);
    float4 a01 = make_float4(0.f, 0.f, 0.f, 0.f);
    float4 a10 = make_float4(0.f, 0.f, 0.f, 0.f);
    float4 a11 = make_float4(0.f, 0.f, 0.f, 0.f);
    #pragma unroll 3
    for (int h = 0; h < HH; ++h) {
        const float  mm0 = s_mid[wave * 2][h];       // LDS broadcast
        const float  mm1 = s_mid[wave * 2 + 1][h];
        const float4* wrow = (const float4*)(w2 + (size_t)h * DD);
        const float4 w20 = wrow[lane];               // 1 KB coalesced
        const float4 w21 = wrow[lane + 64];
        a00.x += mm0 * w20.x; a00.y += mm0 * w20.y; a00.z += mm0 * w20.z; a00.w += mm0 * w20.w;
        a01.x += mm0 * w21.x; a01.y += mm0 * w21.y; a01.z += mm0 * w21.z; a01.w += mm0 * w21.w;
        a10.x += mm1 * w20.x; a10.y += mm1 * w20.y; a10.z += mm1 * w20.z; a10.w += mm1 * w20.w;
        a11.x += mm1 * w21.x; a11.y += mm1 * w21.y; a11.z += mm1 * w21.z; a11.w += mm1 * w21.w;
    }
    {
        const float4 bb0 = ((const float4*)b2)[lane];
        const float4 bb1 = ((const float4*)b2)[lane + 64];
        const float4 qq0 = ((const float4*)(q + (size_t)r0 * DD))[lane];
        const float4 qq1 = ((const float4*)(q + (size_t)r0 * DD))[lane + 64];
        const float4 qq2 = ((const float4*)(q + (size_t)r1 * DD))[lane];
        const float4 qq3 = ((const float4*)(q + (size_t)r1 * DD))[lane + 64];
        float4 o;
        float4* o0 = (float4*)(out + (size_t)r0 * DD);
        float4* o1 = (float4*)(out + (size_t)r1 * DD);
        o.x = a00.x + bb0.x + qq0.x; o.y = a00.y + bb0.y + qq0.y;
        o.z = a00.z + bb0.z + qq0.z; o.w = a00.w + bb0.w + qq0.w;
        o0[lane] = o;
        o.x = a01.x + bb1.x + qq1.x; o.y = a01.y + bb1.y + qq1.y;
        o.z = a01.z + bb1.z + qq1.z; o.w = a01.w + bb1.w + qq1.w;
        o0[lane + 64] = o;
        o.x = a10.x + bb0.x + qq2.x; o.y = a10.y + bb0.y + qq2.y;
        o.z = a10.z + bb0.z + qq2.z; o.w = a10.w + bb0.w + qq2.w;
        o1[lane] = o;
        o.x = a11.x + bb1.x + qq3.x; o.y = a11.y + bb1.y + qq3.y;
        o.z = a11.z + bb1.z + qq3.z; o.w = a11.w + bb1.w + qq3.w;
        o1[lane + 64] = o;
    }
}

// ---------------- Fallback: R3 monolithic (known-good 72.9 us) --------------
__global__ __launch_bounds__(512) void mono_kernel(
    const float* __restrict__ q,
    const int*   __restrict__ heads,
    const int*   __restrict__ tails,
    const int*   __restrict__ rels,
    const float* __restrict__ ent,
    const float* __restrict__ rel,
    const float* __restrict__ w1,
    const float* __restrict__ b1,
    const float* __restrict__ w2,
    const float* __restrict__ b2,
    float* __restrict__ out)
{
    const int b    = blockIdx.x;
    const int tid  = threadIdx.x;
    const int wave = tid >> 6;
    const int lane = tid & 63;

    __shared__ float  s_q[DD];
    __shared__ float4 s_pp[8][128];
    __shared__ float  s_pool[DD];
    __shared__ float  s_wred[8][HH];
    __shared__ float  s_mid[HH];
    __shared__ int    s_h[CC], s_t[CC], s_r[CC];

    if (tid < CC) {
        s_h[tid] = heads[b * CC + tid];
        s_t[tid] = tails[b * CC + tid];
        s_r[tid] = rels [b * CC + tid];
    }
    if (tid < 128) {
        ((float4*)s_q)[tid] = ((const float4*)(q + (size_t)b * DD))[tid];
    }
    __syncthreads();

    const float4 q0 = ((const float4*)s_q)[lane * 2];
    const float4 q1 = ((const float4*)s_q)[lane * 2 + 1];

    float4 acc0 = make_float4(0.f, 0.f, 0.f, 0.f);
    float4 acc1 = make_float4(0.f, 0.f, 0.f, 0.f);
    #pragma unroll 2
    for (int c = wave; c < CC; c += 8) {
        const float4* hrow = (const float4*)(ent + (size_t)s_h[c] * DD);
        const float4* trow = (const float4*)(ent + (size_t)s_t[c] * DD);
        const float4* rrow = (const float4*)(rel + (size_t)s_r[c] * DD);
        const float4 h0 = hrow[lane * 2];
        const float4 h1 = hrow[lane * 2 + 1];
        const float4 t0 = trow[lane * 2];
        const float4 t1 = trow[lane * 2 + 1];
        const float4 r0 = rrow[lane * 2];
        const float4 r1 = rrow[lane * 2 + 1];
        float p = dot4(q0, h0) + dot4(q1, h1);
        #pragma unroll
        for (int off = 32; off > 0; off >>= 1) p += __shfl_xor(p, off, 64);
        acc0.x += p * (t0.x + r0.x);
        acc0.y += p * (t0.y + r0.y);
        acc0.z += p * (t0.z + r0.z);
        acc0.w += p * (t0.w + r0.w);
        acc1.x += p * (t1.x + r1.x);
        acc1.y += p * (t1.y + r1.y);
        acc1.z += p * (t1.z + r1.z);
        acc1.w += p * (t1.w + r1.w);
    }
    s_pp[wave][lane * 2]     = acc0;
    s_pp[wave][lane * 2 + 1] = acc1;
    __syncthreads();

    if (tid < 128) {
        float4 s = s_pp[0][tid];
        #pragma unroll
        for (int w = 1; w < 8; ++w) {
            const float4 a = s_pp[w][tid];
            s.x += a.x; s.y += a.y; s.z += a.z; s.w += a.w;
        }
        ((float4*)s_pool)[tid] = s;
    }
    __syncthreads();

    if (lane < HH) {
        const int d0 = wave * 64;
        float partial = 0.f;
        #pragma unroll 8
        for (int j = 0; j < 64; ++j) {
            partial += s_pool[d0 + j] * w1[(size_t)(d0 + j) * HH + lane];
        }
        s_wred[wave][lane] = partial;
    }
    __syncthreads();
    if (tid < HH) {
        float m = b1[tid];
        #pragma unroll
        for (int w = 0; w < 8; ++w) m += s_wred[w][tid];
        s_mid[tid] = m > 0.f ? m : 0.f;
    }
    __syncthreads();

    const int cg = tid >> 7;
    const int dv = tid & 127;
    float4 acc2 = make_float4(0.f, 0.f, 0.f, 0.f);
    #pragma unroll
    for (int i = 0; i < 13; ++i) {
        const int h = cg + i * 4;
        if (h < HH) {
            const float  m  = s_mid[h];
            const float4 wv = ((const float4*)(w2 + (size_t)h * DD))[dv];
            acc2.x += m * wv.x;
            acc2.y += m * wv.y;
            acc2.z += m * wv.z;
            acc2.w += m * wv.w;
        }
    }
    float4 (*s_red4)[128] = (float4 (*)[128])s_pp;
    s_red4[cg][dv] = acc2;
    __syncthreads();
    if (tid < 128) {
        const float4 a0 = s_red4[0][tid];
        const float4 a1 = s_red4[1][tid];
        const float4 a2 = s_red4[2][tid];
        const float4 a3 = s_red4[3][tid];
        const float4 bb = ((const float4*)b2)[tid];
        const float4 qq = ((const float4*)s_q)[tid];
        float4 o;
        o.x = a0.x + a1.x + a2.x + a3.x + bb.x + qq.x;
        o.y = a0.y + a1.y + a2.y + a3.y + bb.y + qq.y;
        o.z = a0.z + a1.z + a2.z + a3.z + bb.z + qq.z;
        o.w = a0.w + a1.w + a2.w + a3.w + bb.w + qq.w;
        ((float4*)(out + (size_t)b * DD))[tid] = o;
    }
}

extern "C" void kernel_launch(void* const* d_in, const int* in_sizes, int n_in,
                              void* d_out, int out_size, void* d_ws, size_t ws_size,
                              hipStream_t stream) {
    const float* q     = (const float*)d_in[0];
    const int*   heads = (const int*)  d_in[1];
    const int*   tails = (const int*)  d_in[2];
    const int*   rels  = (const int*)  d_in[3];
    const float* ent   = (const float*)d_in[4];
    const float* rel   = (const float*)d_in[5];
    const float* w1    = (const float*)d_in[6];
    const float* b1    = (const float*)d_in[7];
    const float* w2    = (const float*)d_in[8];
    const float* b2    = (const float*)d_in[9];
    float* out = (float*)d_out;

    const size_t need = (size_t)BB * DD * sizeof(float);  // 4 MB pooled
    if (ws_size >= need) {
        float* ws_pool = (float*)d_ws;
        gather_pool_kernel<<<BB, 512, 0, stream>>>(q, heads, tails, rels,
                                                   ent, rel, ws_pool);
        ffn_kernel<<<BB / RPB, 512, 0, stream>>>(q, ws_pool, w1, b1, w2, b2, out);
    } else {
        mono_kernel<<<BB, 512, 0, stream>>>(q, heads, tails, rels, ent, rel,
                                            w1, b1, w2, b2, out);
    }
}

// Round 9
// 74.069 us; speedup vs baseline: 1.3006x; 1.3006x over previous
//
#include <hip/hip_runtime.h>

// Problem constants (fixed by the reference)
#define BB 2048
#define CC 50
#define DD 512
#define HH 51   // D // 10

static __device__ __forceinline__ float dot4(const float4 a, const float4 b) {
    return a.x * b.x + a.y * b.y + a.z * b.z + a.w * b.w;
}

// R3 proven monolithic kernel, byte-identical body; ONLY change:
// __launch_bounds__(512, 8) -> forces VGPR <= 64, 4 blocks/CU (32 waves/CU)
// instead of VGPR=68 -> 2 blocks/CU (16 waves/CU). Latency-bound gather
// should scale with resident waves.
__global__ __launch_bounds__(512, 8) void ConstraintFuser_kernel(
    const float* __restrict__ q,      // [B, D]
    const int*   __restrict__ heads,  // [B, C]
    const int*   __restrict__ tails,  // [B, C]
    const int*   __restrict__ rels,   // [B, C]
    const float* __restrict__ ent,    // [NE+1, D]
    const float* __restrict__ rel,    // [NR+1, D]
    const float* __restrict__ w1,     // [D, H]
    const float* __restrict__ b1,     // [H]
    const float* __restrict__ w2,     // [H, D]
    const float* __restrict__ b2,     // [D]
    float* __restrict__ out)          // [B, D]
{
    const int b    = blockIdx.x;
    const int tid  = threadIdx.x;
    const int wave = tid >> 6;
    const int lane = tid & 63;

    __shared__ float  s_q[DD];           // 2 KB
    __shared__ float4 s_pp[8][128];      // 16 KB — per-wave pooled partials; reused for epilogue reduce
    __shared__ float  s_pool[DD];        // 2 KB
    __shared__ float  s_wred[8][HH];
    __shared__ float  s_mid[HH];
    __shared__ int    s_h[CC], s_t[CC], s_r[CC];

    // ---- stage indices + query row ----
    if (tid < CC) {
        s_h[tid] = heads[b * CC + tid];
        s_t[tid] = tails[b * CC + tid];
        s_r[tid] = rels [b * CC + tid];
    }
    if (tid < 128) {
        ((float4*)s_q)[tid] = ((const float4*)(q + (size_t)b * DD))[tid];
    }
    __syncthreads();

    const float4 q0 = ((const float4*)s_q)[lane * 2];
    const float4 q1 = ((const float4*)s_q)[lane * 2 + 1];

    // ---- merged score + pool stream (barrier-free, per-wave) ----
    float4 acc0 = make_float4(0.f, 0.f, 0.f, 0.f);
    float4 acc1 = make_float4(0.f, 0.f, 0.f, 0.f);
    #pragma unroll 2
    for (int c = wave; c < CC; c += 8) {
        const float4* hrow = (const float4*)(ent + (size_t)s_h[c] * DD);
        const float4* trow = (const float4*)(ent + (size_t)s_t[c] * DD);
        const float4* rrow = (const float4*)(rel + (size_t)s_r[c] * DD);
        const float4 h0 = hrow[lane * 2];
        const float4 h1 = hrow[lane * 2 + 1];
        const float4 t0 = trow[lane * 2];
        const float4 t1 = trow[lane * 2 + 1];
        const float4 r0 = rrow[lane * 2];
        const float4 r1 = rrow[lane * 2 + 1];
        float p = dot4(q0, h0) + dot4(q1, h1);
        #pragma unroll
        for (int off = 32; off > 0; off >>= 1) p += __shfl_xor(p, off, 64);
        acc0.x += p * (t0.x + r0.x);
        acc0.y += p * (t0.y + r0.y);
        acc0.z += p * (t0.z + r0.z);
        acc0.w += p * (t0.w + r0.w);
        acc1.x += p * (t1.x + r1.x);
        acc1.y += p * (t1.y + r1.y);
        acc1.z += p * (t1.z + r1.z);
        acc1.w += p * (t1.w + r1.w);
    }
    s_pp[wave][lane * 2]     = acc0;
    s_pp[wave][lane * 2 + 1] = acc1;
    __syncthreads();

    // ---- reduce 8 per-wave partials -> s_pool ----
    if (tid < 128) {
        float4 s = s_pp[0][tid];
        #pragma unroll
        for (int w = 1; w < 8; ++w) {
            const float4 a = s_pp[w][tid];
            s.x += a.x; s.y += a.y; s.z += a.z; s.w += a.w;
        }
        ((float4*)s_pool)[tid] = s;
    }
    __syncthreads();

    // ---- phase 3: mid = relu(pooled @ w1 + b1); wave w owns d in [64w, 64w+64) ----
    if (lane < HH) {
        const int d0 = wave * 64;
        float partial = 0.f;
        #pragma unroll 8
        for (int j = 0; j < 64; ++j) {
            partial += s_pool[d0 + j] * w1[(size_t)(d0 + j) * HH + lane];
        }
        s_wred[wave][lane] = partial;
    }
    __syncthreads();
    if (tid < HH) {
        float m = b1[tid];
        #pragma unroll
        for (int w = 0; w < 8; ++w) m += s_wred[w][tid];
        s_mid[tid] = m > 0.f ? m : 0.f;
    }
    __syncthreads();

    // ---- phase 4: out = mid @ w2 + b2 + q ----
    const int cg = tid >> 7;    // 0..3
    const int dv = tid & 127;   // float4 index within row
    float4 acc2 = make_float4(0.f, 0.f, 0.f, 0.f);
    #pragma unroll
    for (int i = 0; i < 13; ++i) {
        const int h = cg + i * 4;
        if (h < HH) {
            const float  m  = s_mid[h];
            const float4 wv = ((const float4*)(w2 + (size_t)h * DD))[dv];
            acc2.x += m * wv.x;
            acc2.y += m * wv.y;
            acc2.z += m * wv.z;
            acc2.w += m * wv.w;
        }
    }
    float4 (*s_red4)[128] = (float4 (*)[128])s_pp;   // reuse dead LDS
    s_red4[cg][dv] = acc2;
    __syncthreads();
    if (tid < 128) {
        const float4 a0 = s_red4[0][tid];
        const float4 a1 = s_red4[1][tid];
        const float4 a2 = s_red4[2][tid];
        const float4 a3 = s_red4[3][tid];
        const float4 bb = ((const float4*)b2)[tid];
        const float4 qq = ((const float4*)s_q)[tid];
        float4 o;
        o.x = a0.x + a1.x + a2.x + a3.x + bb.x + qq.x;
        o.y = a0.y + a1.y + a2.y + a3.y + bb.y + qq.y;
        o.z = a0.z + a1.z + a2.z + a3.z + bb.z + qq.z;
        o.w = a0.w + a1.w + a2.w + a3.w + bb.w + qq.w;
        ((float4*)(out + (size_t)b * DD))[tid] = o;
    }
}

extern "C" void kernel_launch(void* const* d_in, const int* in_sizes, int n_in,
                              void* d_out, int out_size, void* d_ws, size_t ws_size,
                              hipStream_t stream) {
    const float* q     = (const float*)d_in[0];
    const int*   heads = (const int*)  d_in[1];
    const int*   tails = (const int*)  d_in[2];
    const int*   rels  = (const int*)  d_in[3];
    const float* ent   = (const float*)d_in[4];
    const float* rel   = (const float*)d_in[5];
    const float* w1    = (const float*)d_in[6];
    const float* b1    = (const float*)d_in[7];
    const float* w2    = (const float*)d_in[8];
    const float* b2    = (const float*)d_in[9];
    float* out = (float*)d_out;

    ConstraintFuser_kernel<<<BB, 512, 0, stream>>>(
        q, heads, tails, rels, ent, rel, w1, b1, w2, b2, out);
}

// Round 10
// 73.302 us; speedup vs baseline: 1.3142x; 1.0105x over previous
//
#include <hip/hip_runtime.h>

// Problem constants (fixed by the reference)
#define BB 2048
#define CC 50
#define DD 512
#define HH 51   // D // 10

static __device__ __forceinline__ float dot4(const float4 a, const float4 b) {
    return a.x * b.x + a.y * b.y + a.z * b.z + a.w * b.w;
}

// R3 monolithic kernel; ONLY change vs R3: gather-phase lane->element mapping
// is [lane], [lane+64] (each load instr = contiguous 1KB, 16 cache lines)
// instead of [lane*2], [lane*2+1] (stride-32B, ~32 lines per instr).
// Halves TA/L1 line-request count for the dominant gather phase.
__global__ __launch_bounds__(512) void ConstraintFuser_kernel(
    const float* __restrict__ q,      // [B, D]
    const int*   __restrict__ heads,  // [B, C]
    const int*   __restrict__ tails,  // [B, C]
    const int*   __restrict__ rels,   // [B, C]
    const float* __restrict__ ent,    // [NE+1, D]
    const float* __restrict__ rel,    // [NR+1, D]
    const float* __restrict__ w1,     // [D, H]
    const float* __restrict__ b1,     // [H]
    const float* __restrict__ w2,     // [H, D]
    const float* __restrict__ b2,     // [D]
    float* __restrict__ out)          // [B, D]
{
    const int b    = blockIdx.x;
    const int tid  = threadIdx.x;
    const int wave = tid >> 6;
    const int lane = tid & 63;

    __shared__ float  s_q[DD];           // 2 KB
    __shared__ float4 s_pp[8][128];      // 16 KB — per-wave pooled partials; reused for epilogue reduce
    __shared__ float  s_pool[DD];        // 2 KB
    __shared__ float  s_wred[8][HH];
    __shared__ float  s_mid[HH];
    __shared__ int    s_h[CC], s_t[CC], s_r[CC];

    // ---- stage indices + query row ----
    if (tid < CC) {
        s_h[tid] = heads[b * CC + tid];
        s_t[tid] = tails[b * CC + tid];
        s_r[tid] = rels [b * CC + tid];
    }
    if (tid < 128) {
        ((float4*)s_q)[tid] = ((const float4*)(q + (size_t)b * DD))[tid];
    }
    __syncthreads();

    // lane's elements: float4 #lane and #(lane+64)
    const float4 q0 = ((const float4*)s_q)[lane];
    const float4 q1 = ((const float4*)s_q)[lane + 64];

    // ---- merged score + pool stream (barrier-free, per-wave) ----
    float4 acc0 = make_float4(0.f, 0.f, 0.f, 0.f);
    float4 acc1 = make_float4(0.f, 0.f, 0.f, 0.f);
    #pragma unroll 2
    for (int c = wave; c < CC; c += 8) {
        const float4* hrow = (const float4*)(ent + (size_t)s_h[c] * DD);
        const float4* trow = (const float4*)(ent + (size_t)s_t[c] * DD);
        const float4* rrow = (const float4*)(rel + (size_t)s_r[c] * DD);
        const float4 h0 = hrow[lane];
        const float4 h1 = hrow[lane + 64];
        const float4 t0 = trow[lane];
        const float4 t1 = trow[lane + 64];
        const float4 r0 = rrow[lane];
        const float4 r1 = rrow[lane + 64];
        float p = dot4(q0, h0) + dot4(q1, h1);
        #pragma unroll
        for (int off = 32; off > 0; off >>= 1) p += __shfl_xor(p, off, 64);
        acc0.x += p * (t0.x + r0.x);
        acc0.y += p * (t0.y + r0.y);
        acc0.z += p * (t0.z + r0.z);
        acc0.w += p * (t0.w + r0.w);
        acc1.x += p * (t1.x + r1.x);
        acc1.y += p * (t1.y + r1.y);
        acc1.z += p * (t1.z + r1.z);
        acc1.w += p * (t1.w + r1.w);
    }
    // s_pp[w][j] = float4 element j of wave-w partial pooled
    s_pp[wave][lane]      = acc0;
    s_pp[wave][lane + 64] = acc1;
    __syncthreads();

    // ---- reduce 8 per-wave partials -> s_pool ----
    if (tid < 128) {
        float4 s = s_pp[0][tid];
        #pragma unroll
        for (int w = 1; w < 8; ++w) {
            const float4 a = s_pp[w][tid];
            s.x += a.x; s.y += a.y; s.z += a.z; s.w += a.w;
        }
        ((float4*)s_pool)[tid] = s;
    }
    __syncthreads();

    // ---- phase 3: mid = relu(pooled @ w1 + b1); wave w owns d in [64w, 64w+64) ----
    if (lane < HH) {
        const int d0 = wave * 64;
        float partial = 0.f;
        #pragma unroll 8
        for (int j = 0; j < 64; ++j) {
            partial += s_pool[d0 + j] * w1[(size_t)(d0 + j) * HH + lane];
        }
        s_wred[wave][lane] = partial;
    }
    __syncthreads();
    if (tid < HH) {
        float m = b1[tid];
        #pragma unroll
        for (int w = 0; w < 8; ++w) m += s_wred[w][tid];
        s_mid[tid] = m > 0.f ? m : 0.f;
    }
    __syncthreads();

    // ---- phase 4: out = mid @ w2 + b2 + q ----
    const int cg = tid >> 7;    // 0..3
    const int dv = tid & 127;   // float4 index within row
    float4 acc2 = make_float4(0.f, 0.f, 0.f, 0.f);
    #pragma unroll
    for (int i = 0; i < 13; ++i) {
        const int h = cg + i * 4;
        if (h < HH) {
            const float  m  = s_mid[h];
            const float4 wv = ((const float4*)(w2 + (size_t)h * DD))[dv];
            acc2.x += m * wv.x;
            acc2.y += m * wv.y;
            acc2.z += m * wv.z;
            acc2.w += m * wv.w;
        }
    }
    float4 (*s_red4)[128] = (float4 (*)[128])s_pp;   // reuse dead LDS
    s_red4[cg][dv] = acc2;
    __syncthreads();
    if (tid < 128) {
        const float4 a0 = s_red4[0][tid];
        const float4 a1 = s_red4[1][tid];
        const float4 a2 = s_red4[2][tid];
        const float4 a3 = s_red4[3][tid];
        const float4 bb = ((const float4*)b2)[tid];
        const float4 qq = ((const float4*)s_q)[tid];
        float4 o;
        o.x = a0.x + a1.x + a2.x + a3.x + bb.x + qq.x;
        o.y = a0.y + a1.y + a2.y + a3.y + bb.y + qq.y;
        o.z = a0.z + a1.z + a2.z + a3.z + bb.z + qq.z;
        o.w = a0.w + a1.w + a2.w + a3.w + bb.w + qq.w;
        ((float4*)(out + (size_t)b * DD))[tid] = o;
    }
}

extern "C" void kernel_launch(void* const* d_in, const int* in_sizes, int n_in,
                              void* d_out, int out_size, void* d_ws, size_t ws_size,
                              hipStream_t stream) {
    const float* q     = (const float*)d_in[0];
    const int*   heads = (const int*)  d_in[1];
    const int*   tails = (const int*)  d_in[2];
    const int*   rels  = (const int*)  d_in[3];
    const float* ent   = (const float*)d_in[4];
    const float* rel   = (const float*)d_in[5];
    const float* w1    = (const float*)d_in[6];
    const float* b1    = (const float*)d_in[7];
    const float* w2    = (const float*)d_in[8];
    const float* b2    = (const float*)d_in[9];
    float* out = (float*)d_out;

    ConstraintFuser_kernel<<<BB, 512, 0, stream>>>(
        q, heads, tails, rels, ent, rel, w1, b1, w2, b2, out);
}